// Round 10
// baseline (10041.877 us; speedup 1.0000x reference)
//
#include <hip/hip_runtime.h>
#include <hip/hip_bf16.h>
#include <stdint.h>

typedef float  f32x16 __attribute__((ext_vector_type(16)));
typedef __bf16 bf16x8 __attribute__((ext_vector_type(8)));
typedef unsigned u32x4 __attribute__((ext_vector_type(4)));

#define NH 1280
#define MAT_ELEMS (80 * NH * 16)   // u16 elems per 1280x1280 matrix

// workspace offsets (bytes)
#define OFF_W1S  0u
#define OFF_W2S  6553600u
#define OFF_W3S  9830400u
#define OFF_HI   13107200u   // 1024x1280 f32
#define OFF_HJB  18350080u   // 1024x1280 f32 (hj + b1)
#define OFF_H2   23592960u   // 256 grps * 20 chunks * 32768 B (slot-layout h2)

__device__ __forceinline__ unsigned short bfb(float f) {
    unsigned u = __builtin_bit_cast(unsigned, f);
    u += 0x7fffu + ((u >> 16) & 1u);          // RNE
    return (unsigned short)(u >> 16);
}
__device__ __forceinline__ unsigned pk2(float lo, float hi) {
    return (unsigned)bfb(lo) | ((unsigned)bfb(hi) << 16);
}
// relu(a), relu(b) -> packed bf16 (HW RNE cvt)
__device__ __forceinline__ unsigned rpk(float a, float b) {
    float s0 = fmaxf(a, 0.f), s1 = fmaxf(b, 0.f);
    unsigned d;
    asm("v_cvt_pk_bf16_f32 %0, %1, %2" : "=v"(d) : "v"(s0), "v"(s1));
    return d;
}

// ---------------------------------------------------------------------------
// k_cvt: f32 row-major -> bf16 MFMA-B fragment-linear (verified).
// ---------------------------------------------------------------------------
__global__ void k_cvt(const float* __restrict__ src, unsigned short* __restrict__ dst) {
    __shared__ float tile[16][257];
    const int kb = blockIdx.x, cb = blockIdx.y, t = threadIdx.x;
#pragma unroll
    for (int r = 0; r < 16; ++r)
        tile[r][t] = src[(size_t)(kb * 16 + r) * NH + cb * 256 + t];
    __syncthreads();
    const int col = cb * 256 + t;
    unsigned u[8];
#pragma unroll
    for (int i = 0; i < 8; ++i) u[i] = pk2(tile[2 * i][t], tile[2 * i + 1][t]);
    u32x4* d = (u32x4*)(dst + ((size_t)kb * NH + col) * 16);
    u32x4 w0 = {u[0], u[1], u[2], u[3]}, w1 = {u[4], u[5], u[6], u[7]};
    d[0] = w0; d[1] = w1;
}

// ---------------------------------------------------------------------------
// k_hihj: Hi = roi@W1[:C]; Hjb = roi@W1[C:] + b1, f32 outputs (verified).
// ---------------------------------------------------------------------------
__device__ __forceinline__ void gemm_half1(const char* aA, unsigned xr, unsigned h16,
                                           const char* bph, f32x16 acc[2][5]) {
    bf16x8 P0[5], P1[5];
#define LDBH1(D_, KL_) { _Pragma("unroll") for (int cf = 0; cf < 5; ++cf) \
    D_[cf] = __builtin_bit_cast(bf16x8, *(const uint4*)(bph + (size_t)(KL_) * 40960 + cf * 1024)); }
#define MF10(P_, KL_) { unsigned ko = ((unsigned)(KL_) * 32u + h16) ^ xr; \
    bf16x8 a0 = __builtin_bit_cast(bf16x8, *(const uint4*)(aA + ko)); \
    bf16x8 a1 = __builtin_bit_cast(bf16x8, *(const uint4*)(aA + 40960 + ko)); \
    _Pragma("unroll") for (int cf = 0; cf < 5; ++cf) { \
        acc[0][cf] = __builtin_amdgcn_mfma_f32_32x32x16_bf16(a0, P_[cf], acc[0][cf], 0, 0, 0); \
        acc[1][cf] = __builtin_amdgcn_mfma_f32_32x32x16_bf16(a1, P_[cf], acc[1][cf], 0, 0, 0); } }
    LDBH1(P0, 0) LDBH1(P1, 1)
    for (int kl = 0; kl < 38; kl += 2) {
        MF10(P0, kl)     LDBH1(P0, kl + 2)
        MF10(P1, kl + 1) LDBH1(P1, kl + 3)
    }
    MF10(P0, 38) MF10(P1, 39)
#undef LDBH1
#undef MF10
}

__global__ __launch_bounds__(512, 2) void k_hihj(const float* __restrict__ roi, const float* __restrict__ b1,
                                                 const unsigned short* __restrict__ w1s,
                                                 float* __restrict__ Hi, float* __restrict__ Hjb) {
    __shared__ __align__(16) char lds[81920];
    const int b = blockIdx.x >> 1, hh = blockIdx.x & 1, tid = threadIdx.x;
    const float* src = roi + (size_t)b * 64 * NH;
    const int wave = tid >> 6, lane = tid & 63, rlo = lane & 31, hsel = lane >> 5;
    const int colbase = wave * 160;
    const unsigned xr = (unsigned)(rlo & 7) << 4, h16 = (unsigned)hsel * 16u;
    const char* aA = lds + rlo * 1280;
    const char* bp = (const char*)(w1s + (size_t)hh * MAT_ELEMS) + (size_t)(colbase + rlo) * 32 + (size_t)hsel * 16;
    f32x16 acc[2][5];
#pragma unroll
    for (int rr = 0; rr < 2; ++rr)
#pragma unroll
        for (int c = 0; c < 5; ++c)
#pragma unroll
            for (int i = 0; i < 16; ++i) acc[rr][c][i] = 0.f;
    for (int kh = 0; kh < 2; ++kh) {
        if (kh) __syncthreads();
        for (int q = 0; q < 10; ++q) {
            int cid = tid + (q << 9);
            int row = cid / 80, kc = cid - row * 80;
            int k = kc * 8, col = kh * 640 + k;
            const float* r = src + row * NH + col;
            float4 v0 = *(const float4*)r, v1 = *(const float4*)(r + 4);
            uint4 pk;
            pk.x = pk2(v0.x, v0.y); pk.y = pk2(v0.z, v0.w);
            pk.z = pk2(v1.x, v1.y); pk.w = pk2(v1.z, v1.w);
            *(uint4*)(lds + row * 1280 + (((unsigned)(k << 1)) ^ ((unsigned)(row & 7) << 4))) = pk;
        }
        __syncthreads();
        gemm_half1(aA, xr, h16, bp + (size_t)kh * 40 * 40960, acc);
    }
    float bias[5];
#pragma unroll
    for (int cf = 0; cf < 5; ++cf) bias[cf] = hh ? b1[colbase + cf * 32 + rlo] : 0.f;
    float* dst = hh ? Hjb : Hi;
#pragma unroll
    for (int rf = 0; rf < 2; ++rf)
#pragma unroll
        for (int cf = 0; cf < 5; ++cf) {
            int col = colbase + cf * 32 + rlo;
#pragma unroll
            for (int j = 0; j < 16; ++j) {
                int row = rf * 32 + (j & 3) + ((j >> 2) << 3) + (hsel << 2);
                dst[(size_t)(b * 64 + row) * NH + col] = acc[rf][cf][j] + bias[cf];
            }
        }
}

// ---------------------------------------------------------------------------
// New GEMM core: WG = 256 rows x 256 cols, 8 waves as 4 rw x 2 cw,
// per wave rf=2 (rows rw*64+{0,32}) x cf=4 (cols cw*128+cf*32), acc[2][4]=128.
// A-chunk = 64 K-cols in slot layout [8 slots of 8k][256 rows][16B]:
// A-frag reads are contiguous 16B runs -> bank-conflict-free.
// ---------------------------------------------------------------------------
#define LDB4(D_, GKB_) { _Pragma("unroll") for (int cf = 0; cf < 4; ++cf) \
    D_[cf] = __builtin_bit_cast(bf16x8, *(const uint4*)(bp + (size_t)(GKB_) * 40960 + cf * 1024)); }

#define GSTEP4(P_, KB_) { \
    const char* as_ = ab + ((KB_) * 2 + hsel) * 4096; \
    bf16x8 a0 = __builtin_bit_cast(bf16x8, *(const uint4*)(as_ + arow0)); \
    bf16x8 a1 = __builtin_bit_cast(bf16x8, *(const uint4*)(as_ + arow1)); \
    acc[0][0] = __builtin_amdgcn_mfma_f32_32x32x16_bf16(a0, P_[0], acc[0][0], 0, 0, 0); \
    acc[0][1] = __builtin_amdgcn_mfma_f32_32x32x16_bf16(a0, P_[1], acc[0][1], 0, 0, 0); \
    acc[0][2] = __builtin_amdgcn_mfma_f32_32x32x16_bf16(a0, P_[2], acc[0][2], 0, 0, 0); \
    acc[0][3] = __builtin_amdgcn_mfma_f32_32x32x16_bf16(a0, P_[3], acc[0][3], 0, 0, 0); \
    acc[1][0] = __builtin_amdgcn_mfma_f32_32x32x16_bf16(a1, P_[0], acc[1][0], 0, 0, 0); \
    acc[1][1] = __builtin_amdgcn_mfma_f32_32x32x16_bf16(a1, P_[1], acc[1][1], 0, 0, 0); \
    acc[1][2] = __builtin_amdgcn_mfma_f32_32x32x16_bf16(a1, P_[2], acc[1][2], 0, 0, 0); \
    acc[1][3] = __builtin_amdgcn_mfma_f32_32x32x16_bf16(a1, P_[3], acc[1][3], 0, 0, 0); \
    LDB4(P_, kc * 4 + (KB_) + 2) }

// one n-row of the staged h1 image: 8 k bf16 from Hi-regs + LDS-staged Hj
#define COMPUTE_N(WB_, HJ_, N_) { \
    float4 j0 = *(const float4*)((HJ_) + (N_) * 256 + c8 * 32); \
    float4 j1 = *(const float4*)((HJ_) + (N_) * 256 + c8 * 32 + 16); \
    uint4 w_; \
    w_.x = rpk(hA0.x + j0.x, hA0.y + j0.y); \
    w_.y = rpk(hA0.z + j0.z, hA0.w + j0.w); \
    w_.z = rpk(hA1.x + j1.x, hA1.y + j1.y); \
    w_.w = rpk(hA1.z + j1.z, hA1.w + j1.w); \
    *(uint4*)((WB_) + c8 * 4096 + ((N_) * 64 + m) * 16) = w_; }

// ---------------------------------------------------------------------------
// k_g1: grp = 256 rows (4n x 64m), cb = 256-col window of h2.
// Deduped staging: Hi loaded once per (m,k-octet) thread; Hj (1KB/chunk)
// double-buffered in LDS. h2 -> slot-layout 32KB chunks in ws.
// ---------------------------------------------------------------------------
__global__ __launch_bounds__(512, 4) void k_g1(const float* __restrict__ Hi,
                                               const float* __restrict__ Hjb,
                                               const float* __restrict__ b2,
                                               const unsigned short* __restrict__ w2s,
                                               char* __restrict__ h2g) {
    __shared__ __align__(16) char lds[67584];
    char* hjA = lds + 65536;
    char* hjB = lds + 66560;
    const int wg = blockIdx.x;
    const int grp = wg / 5, cb = wg - grp * 5;
    const int b = grp >> 4, ng = grp & 15;
    const int tid = threadIdx.x;
    const int wave = tid >> 6, lane = tid & 63, rlo = lane & 31, hsel = lane >> 5;
    const int rw = wave >> 1, cw = wave & 1;
    const char* bp = (const char*)w2s + (size_t)(cb * 256 + cw * 128 + rlo) * 32 + (size_t)hsel * 16;
    const unsigned arow0 = (unsigned)(rw * 64 + rlo) * 16u;
    const unsigned arow1 = arow0 + 512u;
    const int m = tid >> 3, c8 = tid & 7;
    const float* hisrc = Hi + (size_t)(b * 64 + m) * NH + c8 * 8;
    const float* hjsrc = Hjb + (size_t)(b * 64 + ng * 4) * NH;

    f32x16 acc[2][4];
#pragma unroll
    for (int fr = 0; fr < 2; ++fr)
#pragma unroll
        for (int c = 0; c < 4; ++c)
#pragma unroll
            for (int i = 0; i < 16; ++i) acc[fr][c][i] = 0.f;

    bf16x8 P0[4], P1[4];
    LDB4(P0, 0) LDB4(P1, 1)

    float4 hA0, hA1;
    // ---- prologue: build img0 (chunk 0), stage hj for chunk 1 ----
    if (tid < 64)
        *(float4*)(hjA + tid * 16) =
            *(const float4*)(hjsrc + (size_t)(tid >> 4) * NH + (tid & 15) * 4);
    hA0 = *(const float4*)(hisrc);
    hA1 = *(const float4*)(hisrc + 4);
    __syncthreads();
    COMPUTE_N(lds, hjA, 0) COMPUTE_N(lds, hjA, 1) COMPUTE_N(lds, hjA, 2) COMPUTE_N(lds, hjA, 3)
    if (tid < 64)
        *(float4*)(hjB + tid * 16) =
            *(const float4*)(hjsrc + (size_t)(tid >> 4) * NH + 64 + (tid & 15) * 4);
    hA0 = *(const float4*)(hisrc + 64);
    hA1 = *(const float4*)(hisrc + 68);
    __syncthreads();

    for (int kc = 0; kc < 20; ++kc) {
        const char* ab = (kc & 1) ? lds + 32768 : lds;
        char* wbuf = (kc & 1) ? lds : lds + 32768;
        const char* hjc = ((kc + 1) & 1) ? hjB : hjA;
        char* hjn = (kc & 1) ? hjB : hjA;
        const bool build = kc < 19, ld2 = kc < 18;
        if (ld2 && tid < 64)
            *(float4*)(hjn + tid * 16) =
                *(const float4*)(hjsrc + (size_t)(tid >> 4) * NH + (kc + 2) * 64 + (tid & 15) * 4);
        GSTEP4(P0, 0) GSTEP4(P1, 1)
        if (build) { COMPUTE_N(wbuf, hjc, 0) COMPUTE_N(wbuf, hjc, 1) }
        GSTEP4(P0, 2) GSTEP4(P1, 3)
        if (build) { COMPUTE_N(wbuf, hjc, 2) COMPUTE_N(wbuf, hjc, 3) }
        if (ld2) {
            hA0 = *(const float4*)(hisrc + (kc + 2) * 64);
            hA1 = *(const float4*)(hisrc + (kc + 2) * 64 + 4);
        }
        __syncthreads();
    }

    // ---- epilogue: relu(acc+b2) -> slot-layout chunks, 2 passes ----
    float bv[4];
#pragma unroll
    for (int cf = 0; cf < 4; ++cf) bv[cf] = b2[cb * 256 + cw * 128 + cf * 32 + rlo];
    const int chunkbase = grp * 20 + cb * 4;
#pragma unroll
    for (int p = 0; p < 2; ++p) {
        if (p) __syncthreads();
#pragma unroll
        for (int q = 0; q < 2; ++q) {
            int cf = p * 2 + q;
#pragma unroll
            for (int fr = 0; fr < 2; ++fr)
#pragma unroll
                for (int j = 0; j < 16; ++j) {
                    int r = rw * 64 + fr * 32 + (j & 3) + ((j >> 2) << 3) + (hsel << 2);
                    int c = q * 32 + rlo;
                    *(unsigned short*)(lds + cw * 32768 + (c >> 3) * 4096 + r * 16 + (c & 7) * 2)
                        = bfb(fmaxf(acc[fr][cf][j] + bv[cf], 0.f));
                }
        }
        __syncthreads();
#pragma unroll
        for (int q = 0; q < 8; ++q) {
            int idx = tid + (q << 9);        // 16B units, 0..4095
            int h = idx >> 11;
            u32x4 v = *(const u32x4*)(lds + (size_t)idx * 16);
            *(u32x4*)(h2g + (size_t)(chunkbase + h * 2 + p) * 32768 + (size_t)(idx - (h << 11)) * 16) = v;
        }
    }
}

// ---------------------------------------------------------------------------
// k_g2: same geometry; A = pre-swizzled 32KB h2 chunks (pure copy), B = W3.
// Epilogue: relu + row-sum -> LDS psum -> atomicAdd.
// ---------------------------------------------------------------------------
__global__ __launch_bounds__(512, 4) void k_g2(const char* __restrict__ h2g,
                                               const float* __restrict__ b3,
                                               const unsigned short* __restrict__ w3s,
                                               float* __restrict__ out) {
    __shared__ __align__(16) char lds[65536];
    const int wg = blockIdx.x;
    const int grp = wg / 5, cb = wg - grp * 5;
    const int b = grp >> 4;
    const int tid = threadIdx.x;
    const int wave = tid >> 6, lane = tid & 63, rlo = lane & 31, hsel = lane >> 5;
    const int rw = wave >> 1, cw = wave & 1;
    const char* bp = (const char*)w3s + (size_t)(cb * 256 + cw * 128 + rlo) * 32 + (size_t)hsel * 16;
    const unsigned arow0 = (unsigned)(rw * 64 + rlo) * 16u;
    const unsigned arow1 = arow0 + 512u;
    const char* asrc = h2g + (size_t)grp * 20 * 32768;

    f32x16 acc[2][4];
#pragma unroll
    for (int fr = 0; fr < 2; ++fr)
#pragma unroll
        for (int c = 0; c < 4; ++c)
#pragma unroll
            for (int i = 0; i < 16; ++i) acc[fr][c][i] = 0.f;

    bf16x8 P0[4], P1[4];
    LDB4(P0, 0) LDB4(P1, 1)

#pragma unroll
    for (int q = 0; q < 4; ++q) {
        int idx = tid + (q << 9);
        *(u32x4*)(lds + (size_t)idx * 16) = *(const u32x4*)(asrc + (size_t)idx * 16);
    }
    __syncthreads();

    for (int kc = 0; kc < 20; ++kc) {
        const char* ab = (kc & 1) ? lds + 32768 : lds;
        char* wbuf = (kc & 1) ? lds : lds + 32768;
        const bool st = kc < 19;
        u32x4 s0, s1, s2, s3;
        if (st) {
            const char* src = asrc + (size_t)(kc + 1) * 32768;
            s0 = *(const u32x4*)(src + (size_t)tid * 16);
            s1 = *(const u32x4*)(src + (size_t)(tid + 512) * 16);
            s2 = *(const u32x4*)(src + (size_t)(tid + 1024) * 16);
            s3 = *(const u32x4*)(src + (size_t)(tid + 1536) * 16);
        }
        GSTEP4(P0, 0) GSTEP4(P1, 1)
        if (st) {
            *(u32x4*)(wbuf + (size_t)tid * 16) = s0;
            *(u32x4*)(wbuf + (size_t)(tid + 512) * 16) = s1;
        }
        GSTEP4(P0, 2) GSTEP4(P1, 3)
        if (st) {
            *(u32x4*)(wbuf + (size_t)(tid + 1024) * 16) = s2;
            *(u32x4*)(wbuf + (size_t)(tid + 1536) * 16) = s3;
        }
        __syncthreads();
    }

    float b3v[4];
#pragma unroll
    for (int cf = 0; cf < 4; ++cf) b3v[cf] = b3[cb * 256 + cw * 128 + cf * 32 + rlo];
    float cs[4];
#pragma unroll
    for (int cf = 0; cf < 4; ++cf) {
        float s = 0.f;
#pragma unroll
        for (int fr = 0; fr < 2; ++fr)
#pragma unroll
            for (int j = 0; j < 16; ++j) s += fmaxf(acc[fr][cf][j] + b3v[cf], 0.f);
        s += __shfl_xor(s, 32);
        cs[cf] = s;
    }
    float* psum = (float*)lds;   // [4 rw][256 cols]; A-buf dead after final barrier
    __syncthreads();
    if (lane < 32) {
#pragma unroll
        for (int cf = 0; cf < 4; ++cf)
            psum[rw * 256 + cw * 128 + cf * 32 + rlo] = cs[cf];
    }
    __syncthreads();
    if (tid < 256) {
        float t = psum[tid] + psum[256 + tid] + psum[512 + tid] + psum[768 + tid];
        atomicAdd(out + b * NH + cb * 256 + tid, t);
    }
}

extern "C" void kernel_launch(void* const* d_in, const int* in_sizes, int n_in,
                              void* d_out, int out_size, void* d_ws, size_t ws_size,
                              hipStream_t stream) {
    const float* roi = (const float*)d_in[0];
    const float* W1  = (const float*)d_in[1];
    const float* b1  = (const float*)d_in[2];
    const float* W2  = (const float*)d_in[3];
    const float* b2  = (const float*)d_in[4];
    const float* W3  = (const float*)d_in[5];
    const float* b3  = (const float*)d_in[6];
    float* out = (float*)d_out;
    char* ws = (char*)d_ws;
    unsigned short* w1s = (unsigned short*)(ws + OFF_W1S);
    unsigned short* w2s = (unsigned short*)(ws + OFF_W2S);
    unsigned short* w3s = (unsigned short*)(ws + OFF_W3S);
    float* Hi  = (float*)(ws + OFF_HI);
    float* Hjb = (float*)(ws + OFF_HJB);
    char* h2g = ws + OFF_H2;

    (void)hipMemsetAsync(out, 0, (size_t)16 * NH * sizeof(float), stream);

    k_cvt<<<dim3(80, 5), 256, 0, stream>>>(W1, w1s);
    k_cvt<<<dim3(80, 5), 256, 0, stream>>>(W1 + (size_t)NH * NH, w1s + MAT_ELEMS);
    k_cvt<<<dim3(80, 5), 256, 0, stream>>>(W2, w2s);
    k_cvt<<<dim3(80, 5), 256, 0, stream>>>(W3, w3s);

    k_hihj<<<32, 512, 0, stream>>>(roi, b1, w1s, Hi, Hjb);
    k_g1<<<1280, 512, 0, stream>>>(Hi, Hjb, b2, w2s, h2g);
    k_g2<<<1280, 512, 0, stream>>>(h2g, b3, w3s, out);
}

// Round 11
// 496.780 us; speedup vs baseline: 20.2139x; 20.2139x over previous
//
#include <hip/hip_runtime.h>
#include <hip/hip_bf16.h>
#include <stdint.h>

typedef float  f32x16 __attribute__((ext_vector_type(16)));
typedef __bf16 bf16x8 __attribute__((ext_vector_type(8)));
typedef unsigned u32x4 __attribute__((ext_vector_type(4)));

#define NH 1280
#define MAT_ELEMS (80 * NH * 16)   // u16 elems per 1280x1280 matrix

// workspace offsets (bytes)
#define OFF_W1S  0u
#define OFF_W2S  6553600u
#define OFF_W3S  9830400u
#define OFF_HI   13107200u   // 1024x1280 f32
#define OFF_HJB  18350080u   // 1024x1280 f32 (hj + b1)
#define OFF_H2   23592960u   // 256 grps * 20 chunks * 32768 B (swizzled h2)

__device__ __forceinline__ unsigned short bfb(float f) {
    unsigned u = __builtin_bit_cast(unsigned, f);
    u += 0x7fffu + ((u >> 16) & 1u);          // RNE
    return (unsigned short)(u >> 16);
}
__device__ __forceinline__ unsigned pk2(float lo, float hi) {
    return (unsigned)bfb(lo) | ((unsigned)bfb(hi) << 16);
}
// relu(a), relu(b) -> packed bf16 (HW RNE cvt)
__device__ __forceinline__ unsigned rpk(float a, float b) {
    float s0 = fmaxf(a, 0.f), s1 = fmaxf(b, 0.f);
    unsigned d;
    asm("v_cvt_pk_bf16_f32 %0, %1, %2" : "=v"(d) : "v"(s0), "v"(s1));
    return d;
}

// ---------------------------------------------------------------------------
// k_cvt: f32 row-major -> bf16 MFMA-B fragment-linear (verified).
// ---------------------------------------------------------------------------
__global__ void k_cvt(const float* __restrict__ src, unsigned short* __restrict__ dst) {
    __shared__ float tile[16][257];
    const int kb = blockIdx.x, cb = blockIdx.y, t = threadIdx.x;
#pragma unroll
    for (int r = 0; r < 16; ++r)
        tile[r][t] = src[(size_t)(kb * 16 + r) * NH + cb * 256 + t];
    __syncthreads();
    const int col = cb * 256 + t;
    unsigned u[8];
#pragma unroll
    for (int i = 0; i < 8; ++i) u[i] = pk2(tile[2 * i][t], tile[2 * i + 1][t]);
    u32x4* d = (u32x4*)(dst + ((size_t)kb * NH + col) * 16);
    u32x4 w0 = {u[0], u[1], u[2], u[3]}, w1 = {u[4], u[5], u[6], u[7]};
    d[0] = w0; d[1] = w1;
}

// ---------------------------------------------------------------------------
// k_hihj: Hi = roi@W1[:C]; Hjb = roi@W1[C:] + b1, f32 outputs (verified).
// ---------------------------------------------------------------------------
__device__ __forceinline__ void gemm_half1(const char* aA, unsigned xr, unsigned h16,
                                           const char* bph, f32x16 acc[2][5]) {
    bf16x8 P0[5], P1[5];
#define LDBH1(D_, KL_) { _Pragma("unroll") for (int cf = 0; cf < 5; ++cf) \
    D_[cf] = __builtin_bit_cast(bf16x8, *(const uint4*)(bph + (size_t)(KL_) * 40960 + cf * 1024)); }
#define MF10(P_, KL_) { unsigned ko = ((unsigned)(KL_) * 32u + h16) ^ xr; \
    bf16x8 a0 = __builtin_bit_cast(bf16x8, *(const uint4*)(aA + ko)); \
    bf16x8 a1 = __builtin_bit_cast(bf16x8, *(const uint4*)(aA + 40960 + ko)); \
    _Pragma("unroll") for (int cf = 0; cf < 5; ++cf) { \
        acc[0][cf] = __builtin_amdgcn_mfma_f32_32x32x16_bf16(a0, P_[cf], acc[0][cf], 0, 0, 0); \
        acc[1][cf] = __builtin_amdgcn_mfma_f32_32x32x16_bf16(a1, P_[cf], acc[1][cf], 0, 0, 0); } }
    LDBH1(P0, 0) LDBH1(P1, 1)
    for (int kl = 0; kl < 38; kl += 2) {
        MF10(P0, kl)     LDBH1(P0, kl + 2)
        MF10(P1, kl + 1) LDBH1(P1, kl + 3)
    }
    MF10(P0, 38) MF10(P1, 39)
#undef LDBH1
#undef MF10
}

__global__ __launch_bounds__(512, 2) void k_hihj(const float* __restrict__ roi, const float* __restrict__ b1,
                                                 const unsigned short* __restrict__ w1s,
                                                 float* __restrict__ Hi, float* __restrict__ Hjb) {
    __shared__ __align__(16) char lds[81920];
    const int b = blockIdx.x >> 1, hh = blockIdx.x & 1, tid = threadIdx.x;
    const float* src = roi + (size_t)b * 64 * NH;
    const int wave = tid >> 6, lane = tid & 63, rlo = lane & 31, hsel = lane >> 5;
    const int colbase = wave * 160;
    const unsigned xr = (unsigned)(rlo & 7) << 4, h16 = (unsigned)hsel * 16u;
    const char* aA = lds + rlo * 1280;
    const char* bp = (const char*)(w1s + (size_t)hh * MAT_ELEMS) + (size_t)(colbase + rlo) * 32 + (size_t)hsel * 16;
    f32x16 acc[2][5];
#pragma unroll
    for (int rr = 0; rr < 2; ++rr)
#pragma unroll
        for (int c = 0; c < 5; ++c)
#pragma unroll
            for (int i = 0; i < 16; ++i) acc[rr][c][i] = 0.f;
    for (int kh = 0; kh < 2; ++kh) {
        if (kh) __syncthreads();
        for (int q = 0; q < 10; ++q) {
            int cid = tid + (q << 9);
            int row = cid / 80, kc = cid - row * 80;
            int k = kc * 8, col = kh * 640 + k;
            const float* r = src + row * NH + col;
            float4 v0 = *(const float4*)r, v1 = *(const float4*)(r + 4);
            uint4 pk;
            pk.x = pk2(v0.x, v0.y); pk.y = pk2(v0.z, v0.w);
            pk.z = pk2(v1.x, v1.y); pk.w = pk2(v1.z, v1.w);
            *(uint4*)(lds + row * 1280 + (((unsigned)(k << 1)) ^ ((unsigned)(row & 7) << 4))) = pk;
        }
        __syncthreads();
        gemm_half1(aA, xr, h16, bp + (size_t)kh * 40 * 40960, acc);
    }
    float bias[5];
#pragma unroll
    for (int cf = 0; cf < 5; ++cf) bias[cf] = hh ? b1[colbase + cf * 32 + rlo] : 0.f;
    float* dst = hh ? Hjb : Hi;
#pragma unroll
    for (int rf = 0; rf < 2; ++rf)
#pragma unroll
        for (int cf = 0; cf < 5; ++cf) {
            int col = colbase + cf * 32 + rlo;
#pragma unroll
            for (int j = 0; j < 16; ++j) {
                int row = rf * 32 + (j & 3) + ((j >> 2) << 3) + (hsel << 2);
                dst[(size_t)(b * 64 + row) * NH + col] = acc[rf][cf][j] + bias[cf];
            }
        }
}

// ---------------------------------------------------------------------------
// GEMM core: WG = 256 rows x 256 cols; 8 waves = 2 rw x 4 cw; per wave
// rf=4 (rows rw*128+fr*32) x cf=2 (cols cw*64+cf*32); acc[4][2]=128 regs.
// A-chunk = 64 K-cols as [slot s=octet][row r] 16B runs, SWIZZLED:
// phys = s*4096 + ((r ^ s)*16)  -> writes hit 8 distinct bank-quads,
// reads stay conflict-free ((r*16)^(s*16) == ((r^s)*16)).
// ---------------------------------------------------------------------------
#define LDB2(D_, GKB_) { _Pragma("unroll") for (int cf = 0; cf < 2; ++cf) \
    D_[cf] = __builtin_bit_cast(bf16x8, *(const uint4*)(bp + (size_t)(GKB_) * 40960 + cf * 1024)); }

#define GSTEP(P_, KB_) { \
    const char* as_ = ab + ((KB_) * 2 + hsel) * 4096; \
    const unsigned sx_ = (unsigned)((KB_) * 32) + h16; \
    bf16x8 a0 = __builtin_bit_cast(bf16x8, *(const uint4*)(as_ + (ar0 ^ sx_))); \
    bf16x8 a1 = __builtin_bit_cast(bf16x8, *(const uint4*)(as_ + (ar1 ^ sx_))); \
    bf16x8 a2 = __builtin_bit_cast(bf16x8, *(const uint4*)(as_ + (ar2 ^ sx_))); \
    bf16x8 a3 = __builtin_bit_cast(bf16x8, *(const uint4*)(as_ + (ar3 ^ sx_))); \
    acc[0][0] = __builtin_amdgcn_mfma_f32_32x32x16_bf16(a0, P_[0], acc[0][0], 0, 0, 0); \
    acc[0][1] = __builtin_amdgcn_mfma_f32_32x32x16_bf16(a0, P_[1], acc[0][1], 0, 0, 0); \
    acc[1][0] = __builtin_amdgcn_mfma_f32_32x32x16_bf16(a1, P_[0], acc[1][0], 0, 0, 0); \
    acc[1][1] = __builtin_amdgcn_mfma_f32_32x32x16_bf16(a1, P_[1], acc[1][1], 0, 0, 0); \
    acc[2][0] = __builtin_amdgcn_mfma_f32_32x32x16_bf16(a2, P_[0], acc[2][0], 0, 0, 0); \
    acc[2][1] = __builtin_amdgcn_mfma_f32_32x32x16_bf16(a2, P_[1], acc[2][1], 0, 0, 0); \
    acc[3][0] = __builtin_amdgcn_mfma_f32_32x32x16_bf16(a3, P_[0], acc[3][0], 0, 0, 0); \
    acc[3][1] = __builtin_amdgcn_mfma_f32_32x32x16_bf16(a3, P_[1], acc[3][1], 0, 0, 0); \
    LDB2(P_, kc * 4 + (KB_) + 2) }

// build one n-row of the next A-chunk: Hi from regs + Hj from LDS broadcast
#define COMPUTE_N(WB_, HJ_, N_) { \
    float4 j0 = *(const float4*)((HJ_) + (N_) * 256 + c8 * 32); \
    float4 j1 = *(const float4*)((HJ_) + (N_) * 256 + c8 * 32 + 16); \
    uint4 w_; \
    w_.x = rpk(hA0.x + j0.x, hA0.y + j0.y); \
    w_.y = rpk(hA0.z + j0.z, hA0.w + j0.w); \
    w_.z = rpk(hA1.x + j1.x, hA1.y + j1.y); \
    w_.w = rpk(hA1.z + j1.z, hA1.w + j1.w); \
    *(uint4*)((WB_) + c8 * 4096 + ((((N_) * 64 + m) ^ c8) * 16)) = w_; }

// ---------------------------------------------------------------------------
// k_g1: cb-major grid; grp = 256 rows (4n x 64m), cb = 256-col window.
// Deduped staging: each Hi element loaded once (thread = (m, k-octet));
// Hj (1KB/chunk) double-buffered in LDS. h2 -> swizzled 32KB chunks in ws.
// ---------------------------------------------------------------------------
__global__ __launch_bounds__(512, 2) void k_g1(const float* __restrict__ Hi,
                                               const float* __restrict__ Hjb,
                                               const float* __restrict__ b2,
                                               const unsigned short* __restrict__ w2s,
                                               char* __restrict__ h2g) {
    __shared__ __align__(16) char lds[67584];
    char* hjA = lds + 65536;
    char* hjB = lds + 66560;
    const int wg = blockIdx.x;
    const int cb = wg >> 8, grp = wg & 255;
    const int b = grp >> 4, ng = grp & 15;
    const int tid = threadIdx.x;
    const int wave = tid >> 6, lane = tid & 63, rlo = lane & 31, hsel = lane >> 5;
    const int rw = wave >> 2, cw = wave & 3;
    const unsigned h16 = (unsigned)hsel * 16u;
    const char* bp = (const char*)w2s + (size_t)(cb * 256 + cw * 64 + rlo) * 32 + (size_t)hsel * 16;
    const unsigned ar0 = (unsigned)(rw * 128 + rlo) * 16u;
    const unsigned ar1 = ar0 + 512u, ar2 = ar0 + 1024u, ar3 = ar0 + 1536u;
    const int m = tid >> 3, c8 = tid & 7;
    const float* hisrc = Hi + (size_t)(b * 64 + m) * NH + c8 * 8;
    const float* hjsrc = Hjb + (size_t)(b * 64 + ng * 4) * NH;

    f32x16 acc[4][2];
#pragma unroll
    for (int fr = 0; fr < 4; ++fr)
#pragma unroll
        for (int c = 0; c < 2; ++c)
#pragma unroll
            for (int i = 0; i < 16; ++i) acc[fr][c][i] = 0.f;

    bf16x8 P0[2], P1[2];
    LDB2(P0, 0) LDB2(P1, 1)

    float4 hA0, hA1;
    // ---- prologue: chunk0 -> lds, hj(chunk1) -> hjB, Hi(chunk1) -> regs ----
    if (tid < 64)
        *(float4*)(hjA + tid * 16) =
            *(const float4*)(hjsrc + (size_t)(tid >> 4) * NH + (tid & 15) * 4);
    hA0 = *(const float4*)(hisrc);
    hA1 = *(const float4*)(hisrc + 4);
    __syncthreads();
    COMPUTE_N(lds, hjA, 0) COMPUTE_N(lds, hjA, 1) COMPUTE_N(lds, hjA, 2) COMPUTE_N(lds, hjA, 3)
    if (tid < 64)
        *(float4*)(hjB + tid * 16) =
            *(const float4*)(hjsrc + (size_t)(tid >> 4) * NH + 64 + (tid & 15) * 4);
    hA0 = *(const float4*)(hisrc + 64);
    hA1 = *(const float4*)(hisrc + 68);
    __syncthreads();

    for (int kc = 0; kc < 20; ++kc) {
        const char* ab = (kc & 1) ? lds + 32768 : lds;
        char* wbuf = (kc & 1) ? lds : lds + 32768;
        const char* hjc = ((kc + 1) & 1) ? hjB : hjA;
        char* hjn = (kc & 1) ? hjB : hjA;
        const bool build = kc < 19, ld2 = kc < 18;
        if (ld2 && tid < 64)
            *(float4*)(hjn + tid * 16) =
                *(const float4*)(hjsrc + (size_t)(tid >> 4) * NH + (kc + 2) * 64 + (tid & 15) * 4);
        GSTEP(P0, 0) GSTEP(P1, 1)
        if (build) { COMPUTE_N(wbuf, hjc, 0) COMPUTE_N(wbuf, hjc, 1) }
        GSTEP(P0, 2) GSTEP(P1, 3)
        if (build) { COMPUTE_N(wbuf, hjc, 2) COMPUTE_N(wbuf, hjc, 3) }
        if (ld2) {
            hA0 = *(const float4*)(hisrc + (kc + 2) * 64);
            hA1 = *(const float4*)(hisrc + (kc + 2) * 64 + 4);
        }
        __syncthreads();
    }

    // ---- epilogue: relu(acc+b2) -> swizzled chunks, 2 passes of 2 chunks ----
    float bv[2];
    bv[0] = b2[cb * 256 + cw * 64 + rlo];
    bv[1] = b2[cb * 256 + cw * 64 + 32 + rlo];
    const int chunkbase = grp * 20 + cb * 4;
#pragma unroll
    for (int p = 0; p < 2; ++p) {
        if (p) __syncthreads();
        if ((cw >> 1) == p) {
            char* half = lds + (cw & 1) * 32768;
#pragma unroll
            for (int fr = 0; fr < 4; ++fr)
#pragma unroll
                for (int cf = 0; cf < 2; ++cf)
#pragma unroll
                    for (int j = 0; j < 16; ++j) {
                        int r = rw * 128 + fr * 32 + (j & 3) + ((j >> 2) << 3) + (hsel << 2);
                        int c = cf * 32 + rlo;
                        int s = c >> 3;
                        *(unsigned short*)(half + s * 4096 + ((r ^ s) * 16) + (c & 7) * 2)
                            = bfb(fmaxf(acc[fr][cf][j] + bv[cf], 0.f));
                    }
        }
        __syncthreads();
#pragma unroll
        for (int q = 0; q < 8; ++q) {
            int idx = tid + (q << 9);
            int h = idx >> 11;
            *(u32x4*)(h2g + (size_t)(chunkbase + p * 2 + h) * 32768 + (size_t)(idx & 2047) * 16)
                = *(const u32x4*)(lds + (size_t)idx * 16);
        }
    }
}

// ---------------------------------------------------------------------------
// k_g2: same geometry; A = pre-swizzled 32KB h2 chunks (pure copies), B = W3.
// Epilogue: relu + row-sum -> LDS psum -> atomicAdd.
// ---------------------------------------------------------------------------
__global__ __launch_bounds__(512, 2) void k_g2(const char* __restrict__ h2g,
                                               const float* __restrict__ b3,
                                               const unsigned short* __restrict__ w3s,
                                               float* __restrict__ out) {
    __shared__ __align__(16) char lds[65536];
    const int wg = blockIdx.x;
    const int cb = wg >> 8, grp = wg & 255;
    const int b = grp >> 4;
    const int tid = threadIdx.x;
    const int wave = tid >> 6, lane = tid & 63, rlo = lane & 31, hsel = lane >> 5;
    const int rw = wave >> 2, cw = wave & 3;
    const unsigned h16 = (unsigned)hsel * 16u;
    const char* bp = (const char*)w3s + (size_t)(cb * 256 + cw * 64 + rlo) * 32 + (size_t)hsel * 16;
    const unsigned ar0 = (unsigned)(rw * 128 + rlo) * 16u;
    const unsigned ar1 = ar0 + 512u, ar2 = ar0 + 1024u, ar3 = ar0 + 1536u;
    const char* asrc = h2g + (size_t)grp * 20 * 32768;

    f32x16 acc[4][2];
#pragma unroll
    for (int fr = 0; fr < 4; ++fr)
#pragma unroll
        for (int c = 0; c < 2; ++c)
#pragma unroll
            for (int i = 0; i < 16; ++i) acc[fr][c][i] = 0.f;

    bf16x8 P0[2], P1[2];
    LDB2(P0, 0) LDB2(P1, 1)

#pragma unroll
    for (int q = 0; q < 4; ++q) {
        int idx = tid + (q << 9);
        *(u32x4*)(lds + (size_t)idx * 16) = *(const u32x4*)(asrc + (size_t)idx * 16);
    }
    __syncthreads();

    for (int kc = 0; kc < 20; ++kc) {
        const char* ab = (kc & 1) ? lds + 32768 : lds;
        char* wbuf = (kc & 1) ? lds : lds + 32768;
        const bool st = kc < 19;
        u32x4 s0, s1, s2, s3;
        if (st) {
            const char* src = asrc + (size_t)(kc + 1) * 32768;
            s0 = *(const u32x4*)(src + (size_t)tid * 16);
            s1 = *(const u32x4*)(src + (size_t)(tid + 512) * 16);
            s2 = *(const u32x4*)(src + (size_t)(tid + 1024) * 16);
            s3 = *(const u32x4*)(src + (size_t)(tid + 1536) * 16);
        }
        GSTEP(P0, 0) GSTEP(P1, 1)
        if (st) {
            *(u32x4*)(wbuf + (size_t)tid * 16) = s0;
            *(u32x4*)(wbuf + (size_t)(tid + 512) * 16) = s1;
        }
        GSTEP(P0, 2) GSTEP(P1, 3)
        if (st) {
            *(u32x4*)(wbuf + (size_t)(tid + 1024) * 16) = s2;
            *(u32x4*)(wbuf + (size_t)(tid + 1536) * 16) = s3;
        }
        __syncthreads();
    }

    // epilogue: relu + row-sum across the WG's 256 rows
    float b3v[2];
    b3v[0] = b3[cb * 256 + cw * 64 + rlo];
    b3v[1] = b3[cb * 256 + cw * 64 + 32 + rlo];
    float cs[2];
#pragma unroll
    for (int cf = 0; cf < 2; ++cf) {
        float s = 0.f;
#pragma unroll
        for (int fr = 0; fr < 4; ++fr)
#pragma unroll
            for (int j = 0; j < 16; ++j) s += fmaxf(acc[fr][cf][j] + b3v[cf], 0.f);
        s += __shfl_xor(s, 32);
        cs[cf] = s;
    }
    float* psum = (float*)lds;   // [2 rw][256 cols]; safe: disjoint from kc=19 reads
    if (lane < 32) {
        psum[rw * 256 + cw * 64 + rlo] = cs[0];
        psum[rw * 256 + cw * 64 + 32 + rlo] = cs[1];
    }
    __syncthreads();
    if (tid < 256) {
        atomicAdd(out + b * NH + cb * 256 + tid, psum[tid] + psum[256 + tid]);
    }
}

extern "C" void kernel_launch(void* const* d_in, const int* in_sizes, int n_in,
                              void* d_out, int out_size, void* d_ws, size_t ws_size,
                              hipStream_t stream) {
    const float* roi = (const float*)d_in[0];
    const float* W1  = (const float*)d_in[1];
    const float* b1  = (const float*)d_in[2];
    const float* W2  = (const float*)d_in[3];
    const float* b2  = (const float*)d_in[4];
    const float* W3  = (const float*)d_in[5];
    const float* b3  = (const float*)d_in[6];
    float* out = (float*)d_out;
    char* ws = (char*)d_ws;
    unsigned short* w1s = (unsigned short*)(ws + OFF_W1S);
    unsigned short* w2s = (unsigned short*)(ws + OFF_W2S);
    unsigned short* w3s = (unsigned short*)(ws + OFF_W3S);
    float* Hi  = (float*)(ws + OFF_HI);
    float* Hjb = (float*)(ws + OFF_HJB);
    char* h2g = ws + OFF_H2;

    (void)hipMemsetAsync(out, 0, (size_t)16 * NH * sizeof(float), stream);

    k_cvt<<<dim3(80, 5), 256, 0, stream>>>(W1, w1s);
    k_cvt<<<dim3(80, 5), 256, 0, stream>>>(W1 + (size_t)NH * NH, w1s + MAT_ELEMS);
    k_cvt<<<dim3(80, 5), 256, 0, stream>>>(W2, w2s);
    k_cvt<<<dim3(80, 5), 256, 0, stream>>>(W3, w3s);

    k_hihj<<<32, 512, 0, stream>>>(roi, b1, w1s, Hi, Hjb);
    k_g1<<<1280, 512, 0, stream>>>(Hi, Hjb, b2, w2s, h2g);
    k_g2<<<1280, 512, 0, stream>>>(h2g, b3, w3s, out);
}